// Round 10
// baseline (303.633 us; speedup 1.0000x reference)
//
#include <hip/hip_runtime.h>
#include <hip/hip_bf16.h>
#include <stdint.h>

// Problem dims (fixed by the reference setup_inputs):
//   a_previous [8192, 4096] f32, theta [4096, 4098] f32, aging [4096, 4098] f32
//   out [8192, 4096] f32
#define M_DIM 8192
#define N_DIM 4096
#define K_IN  4096          // n_in
#define NC    (K_IN + 2)    // 4098 theta/aging columns
#define K_DIM (2 * K_IN)    // GEMM K: [a | inv(a)] concatenated, i8 elems (= bytes)

#define BM 256
#define BN 256
#define BKB 128             // K-bytes per tile (i8) -> 128 B rows
#define NT (K_DIM / BKB)    // 64 K-tiles

typedef __attribute__((ext_vector_type(4))) int i32x4;    // 16B A/B fragment
typedef __attribute__((ext_vector_type(16))) int i32x16;  // 32x32 acc

__device__ __forceinline__ float fast_tanh(float y) {
  float e = __expf(2.0f * y);
  return 1.0f - 2.0f * __builtin_amdgcn_rcpf(1.0f + e);
}

__device__ __forceinline__ int q8(float x) {   // round-to-nearest, fits i8 by range
  return (int)__builtin_rintf(x);
}

// ---------------------------------------------------------------------------
// prep_A: A' = [i8(a*127) | i8(inv(a)*127)], shape [8192][8192] i8
// ---------------------------------------------------------------------------
__global__ __launch_bounds__(256) void prep_A(const float* __restrict__ a,
                                              int8_t* __restrict__ Ap) {
  int idx = blockIdx.x * 256 + threadIdx.x;       // one float4 per thread
  int j  = idx >> 10;
  int k4 = (idx & 1023) << 2;
  float4 v = reinterpret_cast<const float4*>(a)[idx];
  float xs[4] = {v.x, v.y, v.z, v.w};
  int lw = 0, rw = 0;
#pragma unroll
  for (int t = 0; t < 4; ++t) {
    float x = xs[t];
    int ql = q8(x * 127.0f);
    float inv = 0.104f - 0.899f * fast_tanh((x + 0.056f) * 3.858f);
    int qr = q8(inv * 127.0f);
    lw |= (ql & 255) << (8 * t);
    rw |= (qr & 255) << (8 * t);
  }
  size_t base = (size_t)j * K_DIM + k4;
  *reinterpret_cast<int*>(Ap + base)        = lw;   // a half
  *reinterpret_cast<int*>(Ap + base + K_IN) = rw;   // inv(a) half
}

// ---------------------------------------------------------------------------
// prep_B: th = st(theta*aging); W = |th|/rowsum; per-row q8 with scale
// 127/max|th_ingemm|; B' = [qWp | qWn] i8; corr[i] f32 exact; sc[i] dequant.
// ---------------------------------------------------------------------------
__global__ __launch_bounds__(256) void prep_B(const float* __restrict__ theta,
                                              const float* __restrict__ aging,
                                              int8_t* __restrict__ Bp,
                                              float* __restrict__ corr,
                                              float* __restrict__ sc) {
  __shared__ float th_s[NC];
  __shared__ float red_s[256];
  __shared__ float red_m[256];
  int i = blockIdx.x;
  int tid = threadIdx.x;
  const float* tr = theta + (size_t)i * NC;
  const float* ar = aging + (size_t)i * NC;
  float psum = 0.f, pmax = 0.f;
  for (int k = tid; k < NC; k += 256) {
    float th = tr[k] * ar[k];
    if (fabsf(th) < 0.01f) th = 0.f;
    th_s[k] = th;
    psum += fabsf(th);
    if (k < K_IN) pmax = fmaxf(pmax, fabsf(th));
  }
  red_s[tid] = psum;
  red_m[tid] = pmax;
  __syncthreads();
  for (int s = 128; s > 0; s >>= 1) {
    if (tid < s) {
      red_s[tid] += red_s[tid + s];
      red_m[tid] = fmaxf(red_m[tid], red_m[tid + s]);
    }
    __syncthreads();
  }
  float inv_sum = 1.0f / red_s[0];
  float maxabs  = red_m[0];
  float qs = 127.0f / maxabs;
  int8_t* out = Bp + (size_t)i * K_DIM;
  for (int k0 = tid * 4; k0 < K_IN; k0 += 1024) {
    int pw = 0, nw = 0;
#pragma unroll
    for (int t = 0; t < 4; ++t) {
      float th = th_s[k0 + t];
      int q = q8(fabsf(th) * qs);
      if (th >= 0.f) pw |= (q & 255) << (8 * t);
      else           nw |= (q & 255) << (8 * t);
    }
    *reinterpret_cast<int*>(out + k0)         = pw;   // Wp (pairs with a)
    *reinterpret_cast<int*>(out + K_IN + k0)  = nw;   // Wn (pairs with inv(a))
  }
  if (tid == 0) {
    float th1 = th_s[K_IN];
    float th2 = th_s[K_IN + 1];
    float w1 = fabsf(th1) * inv_sum;
    float w2 = fabsf(th2) * inv_sum;
    float inv1 = 0.104f - 0.899f * fast_tanh((1.0f + 0.056f) * 3.858f);
    float inv0 = 0.104f - 0.899f * fast_tanh((0.0f + 0.056f) * 3.858f);
    float c = (th1 >= 0.f) ? w1 : w1 * inv1;
    c += (th2 >= 0.f) ? 0.0f : w2 * inv0;
    corr[i] = c;
    sc[i] = maxabs * inv_sum * (1.0f / 16129.0f);   // 1/(127*127)
  }
}

// ---------------------------------------------------------------------------
// gemm_fused (i8, 32x32x32): R9 tile/swizzle/epilogue (absmax-0, 0-conflict
// verified) with the K-loop restructured 4 phases -> 2 phases/K-tile to halve
// barrier+waitcnt overhead (R9 post-mortem: ~330 cyc/K-tile sync residual).
// Per tile W (buf=W&1):
//   p0: ds_read A m0-3 kg (16) + B n0-1 (8... A m01 8 + B n01 8 = 16 reads);
//       stage A(W+1) -> buf^1 (legal: buf^1 A last read W-1 p1, barrier passed)
//       barrier; lgkm0; MFMA m01 x n01 (16, ks-major: 4 indep chains)
//   p1: ds_read A m23 (8); stage B(W+2) -> buf (legal: buf B last read W p0);
//       vmcnt(4) (keeps only B(W+2); forces A(W+1)+B(W+1) done, each had a
//       2-phase lead); barrier; lgkm0; MFMA m23 x n01 (16)
// Prologue: A0,B0,B1 (12 loads); vmcnt(4); barrier. Tail: vmcnt(0) at
// W>=NT-2 (stages stop; drain remaining A(NT-1)).
// ---------------------------------------------------------------------------
__global__ __launch_bounds__(512, 2) void gemm_fused(const int8_t* __restrict__ A,
                                                     const int8_t* __restrict__ B,
                                                     const float* __restrict__ corr,
                                                     const float* __restrict__ sc,
                                                     float* __restrict__ C) {
  extern __shared__ char lds[];   // 131072 B
  const int tid  = threadIdx.x;
  const int lane = tid & 63;
  const int wid  = tid >> 6;     // 0..7
  const int wr   = wid >> 2;     // 0..1  -> M offset wr*128
  const int wc   = wid & 3;      // 0..3  -> N offset wc*64
  const int fr   = lane & 31;    // fragment row/col (32-row tiles)
  const int kg   = lane >> 5;    // k-group 0/1 (16B each)

  // T1: XCD-aware swizzle; nwg = 512, divisible by 8 -> bijective
  const int bid = (int)blockIdx.x;
  const int sw  = (bid & 7) * 64 + (bid >> 3);
  const int bm0 = (sw >> 4) * BM;     // 32 M-blocks
  const int bn0 = (sw & 15) * BN;     // 16 N-blocks

  // staging: linear LDS dest (glds); GLOBAL source slot pre-swizzled with the
  // involution of the read XOR (R9-verified: 0 conflicts, absmax 0)
  const int colsw = (((tid & 7) ^ ((tid >> 3) & 7) ^ ((tid >> 6) & 3)) << 4);
  const int8_t* gA = A + (size_t)(bm0 + (tid >> 3)) * K_DIM + colsw;
  const int8_t* gB = B + (size_t)(bn0 + (tid >> 3)) * K_DIM + colsw;
  const int dst_t = tid * 16;

  // read-side swizzled fragment byte offsets (within a 128B row)
  const int flip = (((fr & 7) ^ ((fr >> 3) & 3)) << 4);
  int csk[4];
#pragma unroll
  for (int ks = 0; ks < 4; ++ks) csk[ks] = (ks * 32 + kg * 16) ^ flip;
  const int aRow = (wr * 128 + fr) * BKB;              // byte offset of frag row
  const int bRow = (wc * 64 + fr) * BKB;

  i32x16 acc[4][2] = {};   // [m-tile][n-tile]

#define STAGE(ISA, H, T) do {                                                        \
    const int8_t* _g = (ISA) ? gA : gB;                                              \
    const size_t _go = (size_t)((H) * 128) * K_DIM + (size_t)(T) * BKB;              \
    char* _l = lds + (((T) & 1) * 65536) + ((ISA) ? 0 : 32768) + (H) * 16384 + dst_t; \
    __builtin_amdgcn_global_load_lds(                                                \
        (const __attribute__((address_space(1))) unsigned int*)(_g + _go),           \
        (__attribute__((address_space(3))) unsigned int*)_l, 16, 0, 0);              \
    __builtin_amdgcn_global_load_lds(                                                \
        (const __attribute__((address_space(1))) unsigned int*)(_g + _go + (size_t)64 * K_DIM), \
        (__attribute__((address_space(3))) unsigned int*)(_l + 8192), 16, 0, 0);     \
  } while (0)

#define MFMA32(a, b, c) __builtin_amdgcn_mfma_i32_32x32x32_i8((a), (b), (c), 0, 0, 0)

  // ---- prologue: tile0 (A0,B0) + B1 (12 loads); vmcnt(4) (B1 stays in flight)
  STAGE(1, 0, 0); STAGE(1, 1, 0); STAGE(0, 0, 0); STAGE(0, 1, 0);
  STAGE(0, 0, 1); STAGE(0, 1, 1);
  asm volatile("s_waitcnt vmcnt(4)" ::: "memory");
  __builtin_amdgcn_s_barrier();

#pragma unroll 2
  for (int W = 0; W < NT; ++W) {
    const char* pa = lds + (W & 1) * 65536 + aRow;
    const char* pb = lds + (W & 1) * 65536 + 32768 + bRow;
    i32x4 af[2][4], bf[2][4];   // af reloaded with m23 at p1

    // ===== phase 0: read A m0-1 (8) + B n0-1 (8); stage A(W+1) | barrier |
    //               MFMA m01 x n01 (16)
#pragma unroll
    for (int m = 0; m < 2; ++m)
#pragma unroll
      for (int ks = 0; ks < 4; ++ks)
        af[m][ks] = *(const i32x4*)(pa + m * 32 * BKB + csk[ks]);
#pragma unroll
    for (int n = 0; n < 2; ++n)
#pragma unroll
      for (int ks = 0; ks < 4; ++ks)
        bf[n][ks] = *(const i32x4*)(pb + n * 32 * BKB + csk[ks]);
    if (W + 1 < NT) { STAGE(1, 0, W + 1); STAGE(1, 1, W + 1); }
    __builtin_amdgcn_s_barrier();
    asm volatile("s_waitcnt lgkmcnt(0)" ::: "memory");
    __builtin_amdgcn_sched_barrier(0);
    __builtin_amdgcn_s_setprio(1);
#pragma unroll
    for (int ks = 0; ks < 4; ++ks)
#pragma unroll
      for (int m = 0; m < 2; ++m)
#pragma unroll
        for (int n = 0; n < 2; ++n)
          acc[m][n] = MFMA32(af[m][ks], bf[n][ks], acc[m][n]);
    __builtin_amdgcn_s_setprio(0);

    // ===== phase 1: read A m2-3 (8); stage B(W+2); vmcnt(4) | barrier |
    //               MFMA m23 x n01 (16)
#pragma unroll
    for (int m = 0; m < 2; ++m)
#pragma unroll
      for (int ks = 0; ks < 4; ++ks)
        af[m][ks] = *(const i32x4*)(pa + (m + 2) * 32 * BKB + csk[ks]);
    if (W + 2 < NT) { STAGE(0, 0, W + 2); STAGE(0, 1, W + 2); }
    if (W < NT - 2) { asm volatile("s_waitcnt vmcnt(4)" ::: "memory"); }
    else            { asm volatile("s_waitcnt vmcnt(0)" ::: "memory"); }
    __builtin_amdgcn_s_barrier();
    asm volatile("s_waitcnt lgkmcnt(0)" ::: "memory");
    __builtin_amdgcn_sched_barrier(0);
    __builtin_amdgcn_s_setprio(1);
#pragma unroll
    for (int ks = 0; ks < 4; ++ks)
#pragma unroll
      for (int m = 0; m < 2; ++m)
#pragma unroll
        for (int n = 0; n < 2; ++n)
          acc[m + 2][n] = MFMA32(af[m][ks], bf[n][ks], acc[m + 2][n]);
    __builtin_amdgcn_s_setprio(0);
  }

  // ---- epilogue: z = acc*sc[n] + corr[n]; activation; store
  // C/D layout (32x32): col = lane&31, row = (reg&3) + 8*(reg>>2) + 4*(lane>>5)
#pragma unroll
  for (int n = 0; n < 2; ++n) {
    const int col = bn0 + wc * 64 + n * 32 + fr;
    const float cr = corr[col];
    const float s  = sc[col];
#pragma unroll
    for (int mi = 0; mi < 4; ++mi) {
      const int rbase = bm0 + wr * 128 + mi * 32 + 4 * kg;
#pragma unroll
      for (int r = 0; r < 16; ++r) {
        const int row = rbase + (r & 3) + 8 * (r >> 2);
        float z = (float)acc[mi][n][r] * s + cr;
        float e = __expf((z - 0.183f) * 48.2f);
        C[(size_t)row * N_DIM + col] = 1.096f - 1.924f * __builtin_amdgcn_rcpf(1.0f + e);
      }
    }
  }
#undef STAGE
#undef MFMA32
}

// ---------------------------------------------------------------------------
extern "C" void kernel_launch(void* const* d_in, const int* in_sizes, int n_in,
                              void* d_out, int out_size, void* d_ws, size_t ws_size,
                              hipStream_t stream) {
  (void)in_sizes; (void)n_in; (void)out_size; (void)ws_size;
  const float* a_prev = (const float*)d_in[0];
  const float* theta  = (const float*)d_in[1];
  const float* aging  = (const float*)d_in[2];
  float* out = (float*)d_out;

  char* ws = (char*)d_ws;
  int8_t* Ap = (int8_t*)ws;                                        // 67.1 MB
  int8_t* Bp = (int8_t*)(ws + (size_t)M_DIM * K_DIM);              // 33.6 MB
  float* corr = (float*)(ws + (size_t)M_DIM * K_DIM + (size_t)N_DIM * K_DIM);
  float* sc   = corr + N_DIM;

  prep_A<<<(M_DIM * K_IN / 4) / 256, 256, 0, stream>>>(a_prev, Ap);
  prep_B<<<N_DIM, 256, 0, stream>>>(theta, aging, Bp, corr, sc);

  (void)hipFuncSetAttribute((const void*)gemm_fused,
                            hipFuncAttributeMaxDynamicSharedMemorySize, 131072);
  gemm_fused<<<dim3((M_DIM / BM) * (N_DIM / BN)), dim3(512), 131072, stream>>>(Ap, Bp, corr, sc, out);
}